// Round 1
// 238.991 us; speedup vs baseline: 1.0532x; 1.0532x over previous
//
#include <hip/hip_runtime.h>
#include <math.h>

typedef _Float16 half8 __attribute__((ext_vector_type(8)));
typedef float    f32x4 __attribute__((ext_vector_type(4)));

#define DIM     128
#define NCODES  1024
#define M_ROWS  (32*64*64)   // 131072
#define MTILE   128          // rows per block in phase 1 (4 waves x 32 rows)
#define NCHUNK  64           // codes per LDS chunk in phase 1
#define M_TEST  3.0e-3f      // flag margin (quantized-score gap)
#define WL_CAP  16384
#define XG      16           // flagged rows per vq_exact block
#define CSTR    132          // f32 LDS stride (528 B, 16B aligned, bank-friendly)

// fl32(v*v), immune to FMA contraction (f64 product exact, one rounding).
__device__ __forceinline__ float sqf(float v) {
    return (float)((double)v * (double)v);
}

// ---------------------------------------------------------------------------
// Prep: blocks 0..511 transpose cb->cbT (f32) and ch (fp16), one elem/thread.
// Blocks 512..515: cc[n] = np axis-0 sequential sum of rounded squares.
// ---------------------------------------------------------------------------
__global__ void vq_prep(const float* __restrict__ cb,
                        float* __restrict__ cbT,
                        _Float16* __restrict__ ch,
                        float* __restrict__ cc,
                        int* __restrict__ cnt) {
    const int b = blockIdx.x;
    if (b < 512) {
        int e = b * 256 + threadIdx.x;      // 0..131071
        int n = e & 1023, k = e >> 10;
        float v = cb[k * NCODES + n];       // coalesced in n
        cbT[n * DIM + k] = v;
        ch[n * DIM + k]  = (_Float16)v;
    } else {
        int n = (b - 512) * 256 + threadIdx.x;   // 0..1023
        float acc = 0.f;
        for (int k = 0; k < DIM; ++k)
            acc = acc + sqf(cb[k * NCODES + n]); // np axis-0 order
        cc[n] = acc;
        if (n == 0) *cnt = 0;
    }
}

// ---------------------------------------------------------------------------
// Phase 1 v2: fp16 MFMA scoring, fused top-2 argmin.
//  - 1024 blocks x 4 waves, 32 rows/wave (2 m-frags): 4 blocks/CU, 16 waves/CU.
//  - B chunks double-buffered in LDS via global_load_lds (async DMA, 16B),
//    one barrier per chunk; chunk c+1 staged while computing chunk c.
//  - LDS layout XOR-swizzled (slot ^= row&7) via pre-swizzled GLOBAL source
//    (DMA dest must stay linear); ds_read_b128 applies the same XOR ->
//    conflict-free B reads, coalesced staging.
// Per-(row,code) arithmetic is bit-identical to the verified kernel:
// same fp16 inputs, same MFMA shape & k-order, same score/pack/top-2 update
// order, so flag behavior (M_TEST) is unchanged.
// ---------------------------------------------------------------------------
__device__ __forceinline__ void stage_chunk(const _Float16* __restrict__ ch,
                                            _Float16* lds,
                                            int chunk, int w, int quad, int lane15) {
#pragma unroll
    for (int i = 0; i < 4; ++i) {
        int r = (w << 4) + (i << 2) + quad;          // code row 0..63 of chunk
        // linear LDS dest (w*4096 + i*1024 bytes, +lane*16 by HW);
        // source slot pre-swizzled so LDS(r,s) holds global (r, s^(r&7)).
        const _Float16* g = ch + (size_t)(chunk * NCHUNK + r) * DIM
                               + ((lane15 ^ (r & 7)) << 3);
        __builtin_amdgcn_global_load_lds(
            (const __attribute__((address_space(1))) void*)g,
            (__attribute__((address_space(3))) void*)(lds + (w << 11) + (i << 9)),
            16, 0, 0);
    }
}

__global__ __launch_bounds__(256, 4) void vq_gemm(const float* __restrict__ x,
                                                  const _Float16* __restrict__ ch,
                                                  const float* __restrict__ cc,
                                                  int* __restrict__ idx,
                                                  int* __restrict__ cnt,
                                                  int* __restrict__ wl) {
    __shared__ _Float16 bs[2][NCHUNK * DIM];   // 2 x 16 KB double buffer

    const int t      = threadIdx.x;
    const int w      = t >> 6;
    const int L      = t & 63;
    const int lane15 = L & 15;
    const int quad   = L >> 4;
    const int rowbase = blockIdx.x * MTILE + w * 32;

    // Kick off chunk-0 DMA before the A-loads so it lands under them.
    stage_chunk(ch, bs[0], 0, w, quad, lane15);

    // A fragments from global x (f32 -> fp16), persistent across chunks.
    half8 af[2][4];
#pragma unroll
    for (int m = 0; m < 2; ++m) {
#pragma unroll
        for (int ks = 0; ks < 4; ++ks) {
            const float* src = x + (size_t)(rowbase + m * 16 + lane15) * DIM
                                 + ks * 32 + quad * 8;
            float4 f0 = *(const float4*)src;
            float4 f1 = *(const float4*)(src + 4);
            half8 h;
            h[0] = (_Float16)f0.x; h[1] = (_Float16)f0.y;
            h[2] = (_Float16)f0.z; h[3] = (_Float16)f0.w;
            h[4] = (_Float16)f1.x; h[5] = (_Float16)f1.y;
            h[6] = (_Float16)f1.z; h[7] = (_Float16)f1.w;
            af[m][ks] = h;
        }
    }

    // Swizzled ds_read offsets (halves): row lane15, slot (4ks+quad)^(lane15&7).
    int roff[4];
#pragma unroll
    for (int ks = 0; ks < 4; ++ks)
        roff[ks] = lane15 * DIM + ((((ks << 2) + quad) ^ (lane15 & 7)) << 3);

    unsigned p1[2][4], p2[2][4];
#pragma unroll
    for (int m = 0; m < 2; ++m)
#pragma unroll
        for (int r = 0; r < 4; ++r) { p1[m][r] = 0xFFFFFFFFu; p2[m][r] = 0xFFFFFFFFu; }

    __syncthreads();   // chunk 0 resident (compiler drains vmcnt before barrier)

#pragma unroll 2
    for (int c = 0; c < NCODES / NCHUNK; ++c) {
        if (c + 1 < NCODES / NCHUNK)
            stage_chunk(ch, bs[(c + 1) & 1], c + 1, w, quad, lane15);   // async

        float cc4[4];
#pragma unroll
        for (int j = 0; j < 4; ++j)
            cc4[j] = cc[c * NCHUNK + j * 16 + lane15] + 4.0f;           // L1-hot

        const _Float16* bp = bs[c & 1];
        f32x4 acc[2][4];
#pragma unroll
        for (int m = 0; m < 2; ++m)
#pragma unroll
            for (int j = 0; j < 4; ++j) {
                f32x4 z = {0.f, 0.f, 0.f, 0.f};
                acc[m][j] = z;
            }

#pragma unroll
        for (int ks = 0; ks < 4; ++ks) {
            half8 bf[4];
#pragma unroll
            for (int j = 0; j < 4; ++j)
                bf[j] = *(const half8*)(bp + (j << 11) + roff[ks]);
#pragma unroll
            for (int j = 0; j < 4; ++j)
#pragma unroll
                for (int m = 0; m < 2; ++m)
                    acc[m][j] = __builtin_amdgcn_mfma_f32_16x16x32_f16(af[m][ks], bf[j], acc[m][j], 0, 0, 0);
        }

#pragma unroll
        for (int j = 0; j < 4; ++j) {
            int col = c * NCHUNK + j * 16 + lane15;
#pragma unroll
            for (int m = 0; m < 2; ++m)
#pragma unroll
                for (int r = 0; r < 4; ++r) {
                    float s = fmaf(-2.0f, acc[m][j][r], cc4[j]);
                    s = fmaxf(s, 0.25f);
                    unsigned up = (__float_as_uint(s) & 0xFFFFFC00u) | (unsigned)col;
                    unsigned a  = p1[m][r];
                    unsigned lo = a < up ? a : up;
                    unsigned hi = a < up ? up : a;
                    p1[m][r] = lo;
                    p2[m][r] = p2[m][r] < hi ? p2[m][r] : hi;
                }
        }
        __syncthreads();   // readers done + chunk c+1 DMA drained (auto vmcnt(0))
    }

    // Cross-lane top-2 merge over the 16 col-lanes.
#pragma unroll
    for (int m = 0; m < 2; ++m)
#pragma unroll
        for (int r = 0; r < 4; ++r) {
            unsigned a1 = p1[m][r], a2 = p2[m][r];
#pragma unroll
            for (int mask = 1; mask <= 8; mask <<= 1) {
                unsigned b1 = (unsigned)__shfl_xor((int)a1, mask, 64);
                unsigned b2 = (unsigned)__shfl_xor((int)a2, mask, 64);
                unsigned n1 = a1 < b1 ? a1 : b1;
                unsigned hi = a1 < b1 ? b1 : a1;
                unsigned mn = a2 < b2 ? a2 : b2;
                unsigned n2 = hi < mn ? hi : mn;
                a1 = n1; a2 = n2;
            }
            if (lane15 == 0) {
                int row = rowbase + m * 16 + quad * 4 + r;
                idx[row] = (int)(a1 & 0x3FFu);
                float s1 = __uint_as_float(a1 & 0xFFFFFC00u);
                float s2 = __uint_as_float(a2 & 0xFFFFFC00u);
                if (s2 - s1 < M_TEST) {
                    int slot = atomicAdd(cnt, 1);
                    if (slot < WL_CAP) wl[slot] = row;
                }
            }
        }
}

// ---------------------------------------------------------------------------
// Phase 2 v2: np-exact rescoring, 16 flagged rows per block, codebook chunks
// staged in LDS (read once per block, not once per row). Thread (r,q) runs
// 4 sequential k-chains (codes q,q+16,q+32,q+48 of each 64-code chunk) —
// identical per-(row,code) np semantics as the verified round-3/4 kernels.
// ---------------------------------------------------------------------------
__global__ __launch_bounds__(256) void vq_exact(const float* __restrict__ x,
                                                const float* __restrict__ cbT,
                                                const float* __restrict__ cc,
                                                const int* __restrict__ cnt,
                                                const int* __restrict__ wl,
                                                int* __restrict__ idx) {
    __shared__ float xsS[XG * CSTR];                 // 16 rows
    __shared__ float cbS[64 * CSTR];                 // 64-code chunk
    __shared__ unsigned long long red[XG][17];

    const int t = threadIdx.x;
    const int r = t >> 4;      // row slot 0..15
    const int q = t & 15;      // code residue 0..15

    int count = *cnt;
    if (count > WL_CAP) count = WL_CAP;
    const int nblk = (count + XG - 1) / XG;

    for (int b = blockIdx.x; b < nblk; b += gridDim.x) {
        int slot = b * XG + r;
        int row  = wl[slot < count ? slot : count - 1];  // clamp: dup rows benign

        __syncthreads();   // previous iteration's readers done
        // Stage 16 x-rows (coalesced 256B runs).
#pragma unroll
        for (int j = 0; j < 8; ++j) {
            int e  = t + 256 * j;     // 0..2047
            int rr = e >> 7, kk = e & 127;
            int sl = b * XG + rr;
            int rw = wl[sl < count ? sl : count - 1];
            xsS[rr * CSTR + kk] = x[(size_t)rw * DIM + kk];
        }
        __syncthreads();

        // xx: numpy pairwise sum, n=128 block, 8 accumulators (verified form).
        const float* xs = &xsS[r * CSTR];
        float r0 = sqf(xs[0]), r1 = sqf(xs[1]), r2 = sqf(xs[2]), r3 = sqf(xs[3]);
        float r4 = sqf(xs[4]), r5 = sqf(xs[5]), r6 = sqf(xs[6]), r7 = sqf(xs[7]);
#pragma unroll
        for (int k = 8; k < DIM; k += 8) {
            r0 = r0 + sqf(xs[k + 0]); r1 = r1 + sqf(xs[k + 1]);
            r2 = r2 + sqf(xs[k + 2]); r3 = r3 + sqf(xs[k + 3]);
            r4 = r4 + sqf(xs[k + 4]); r5 = r5 + sqf(xs[k + 5]);
            r6 = r6 + sqf(xs[k + 6]); r7 = r7 + sqf(xs[k + 7]);
        }
        const float xx = ((r0 + r1) + (r2 + r3)) + ((r4 + r5) + (r6 + r7));

        unsigned long long best = 0xFFFFFFFFFFFFFFFFull;

        for (int chunk = 0; chunk < NCODES / 64; ++chunk) {
            __syncthreads();
            // Stage 64 codes (f32, from cbT[n][k]).
#pragma unroll
            for (int j = 0; j < 8; ++j) {
                int e  = t + 256 * j;         // float4 index 0..2047
                int ci = e >> 5, k4 = e & 31;
                float4 v = ((const float4*)cbT)[(size_t)(chunk * 64 + ci) * 32 + k4];
                *(float4*)&cbS[ci * CSTR + k4 * 4] = v;
            }
            __syncthreads();

            // 4 sequential k-ascending fmaf chains (np/BLAS order per code).
            float a0 = 0.f, a1 = 0.f, a2 = 0.f, a3 = 0.f;
#pragma unroll
            for (int k4 = 0; k4 < 32; ++k4) {
                float4 xv = *(const float4*)&xsS[r * CSTR + k4 * 4];
                float4 c0 = *(const float4*)&cbS[(q +  0) * CSTR + k4 * 4];
                float4 c1 = *(const float4*)&cbS[(q + 16) * CSTR + k4 * 4];
                float4 c2 = *(const float4*)&cbS[(q + 32) * CSTR + k4 * 4];
                float4 c3 = *(const float4*)&cbS[(q + 48) * CSTR + k4 * 4];
                a0 = fmaf(c0.x, xv.x, a0); a0 = fmaf(c0.y, xv.y, a0);
                a0 = fmaf(c0.z, xv.z, a0); a0 = fmaf(c0.w, xv.w, a0);
                a1 = fmaf(c1.x, xv.x, a1); a1 = fmaf(c1.y, xv.y, a1);
                a1 = fmaf(c1.z, xv.z, a1); a1 = fmaf(c1.w, xv.w, a1);
                a2 = fmaf(c2.x, xv.x, a2); a2 = fmaf(c2.y, xv.y, a2);
                a2 = fmaf(c2.z, xv.z, a2); a2 = fmaf(c2.w, xv.w, a2);
                a3 = fmaf(c3.x, xv.x, a3); a3 = fmaf(c3.y, xv.y, a3);
                a3 = fmaf(c3.z, xv.z, a3); a3 = fmaf(c3.w, xv.w, a3);
            }

            float av[4] = {a0, a1, a2, a3};
#pragma unroll
            for (int j = 0; j < 4; ++j) {
                int n = chunk * 64 + q + 16 * j;
                float tt = xx + cc[n];
                float d  = tt - (av[j] + av[j]);
                unsigned u  = __float_as_uint(d);
                unsigned mk = (unsigned)(((int)u) >> 31);
                unsigned f  = u ^ (mk | 0x80000000u);
                unsigned long long key = ((unsigned long long)f << 32) | (unsigned)n;
                best = key < best ? key : best;
            }
        }

        red[r][q] = best;
        __syncthreads();
        if (q == 0) {
            unsigned long long m = red[r][0];
#pragma unroll
            for (int i = 1; i < 16; ++i) {
                unsigned long long o = red[r][i];
                m = o < m ? o : m;
            }
            idx[row] = (int)(m & 0xFFFFFFFFull);
        }
    }
}

// ---------------------------------------------------------------------------
// Phase 3: out = q (codebook column idx[row]); |q - (x + fl(q-x))| <= 4e-7,
// well under the 1e-3 threshold, and skips the 64 MB x read.
// ---------------------------------------------------------------------------
__global__ void vq_out(const float* __restrict__ cbT,
                       const int* __restrict__ idx,
                       float* __restrict__ out) {
    size_t e = (size_t)blockIdx.x * 256 + threadIdx.x;   // float4 index
    int row = (int)(e >> 5);
    int k4  = (int)(e & 31);
    ((float4*)out)[e] = ((const float4*)cbT)[(size_t)idx[row] * 32 + k4];
}

// ---------------------------------------------------------------------------
extern "C" void kernel_launch(void* const* d_in, const int* in_sizes, int n_in,
                              void* d_out, int out_size, void* d_ws, size_t ws_size,
                              hipStream_t stream) {
    const float* x  = (const float*)d_in[0];   // [131072,128] f32
    const float* cb = (const float*)d_in[1];   // [128,1024] f32
    float* out = (float*)d_out;

    char* p = (char*)d_ws;
    float*    cbT = (float*)p;               p += NCODES * DIM * sizeof(float);
    _Float16* ch  = (_Float16*)p;            p += NCODES * DIM * sizeof(_Float16);
    float*    cc  = (float*)p;               p += NCODES * sizeof(float);
    int*      idx = (int*)p;                 p += M_ROWS * sizeof(int);
    int*      cnt = (int*)p;                 p += 16 * sizeof(int);
    int*      wl  = (int*)p;

    vq_prep<<<516, 256, 0, stream>>>(cb, cbT, ch, cc, cnt);
    vq_gemm<<<M_ROWS / MTILE, 256, 0, stream>>>(x, ch, cc, idx, cnt, wl);
    vq_exact<<<512, 256, 0, stream>>>(x, cbT, cc, cnt, wl, idx);
    vq_out<<<(M_ROWS * (DIM / 4)) / 256, 256, 0, stream>>>(cbT, idx, out);
}

// Round 2
// 197.252 us; speedup vs baseline: 1.2761x; 1.2116x over previous
//
#include <hip/hip_runtime.h>
#include <math.h>

typedef _Float16 half8 __attribute__((ext_vector_type(8)));
typedef float    f32x4 __attribute__((ext_vector_type(4)));

#define DIM     128
#define NCODES  1024
#define M_ROWS  (32*64*64)   // 131072
#define MTILE   128          // rows per block in phase 1 (4 waves x 32 rows)
#define NCHUNK  64           // codes per LDS chunk in phase 1
#define M_TEST  3.0e-3f      // flag margin (quantized-score gap)
#define WL_CAP  16384
#define GR      64           // flagged rows per vq_exact block
#define CSTR    132          // f32 LDS stride (528 B, 16B aligned; worst alias 2-way = free)

// fl32(v*v), immune to FMA contraction (f64 product exact, one rounding).
__device__ __forceinline__ float sqf(float v) {
    return (float)((double)v * (double)v);
}

// ---------------------------------------------------------------------------
// Prep: blocks 0..511 transpose cb->cbT (f32) and ch (fp16), one elem/thread.
// Blocks 512..515: cc[n] = np axis-0 sequential sum of rounded squares.
// Blocks 516..579: init bst[] (per-flagged-row best key) to all-ones.
// ---------------------------------------------------------------------------
__global__ void vq_prep(const float* __restrict__ cb,
                        float* __restrict__ cbT,
                        _Float16* __restrict__ ch,
                        float* __restrict__ cc,
                        int* __restrict__ cnt,
                        unsigned long long* __restrict__ bst) {
    const int b = blockIdx.x;
    if (b < 512) {
        int e = b * 256 + threadIdx.x;      // 0..131071
        int n = e & 1023, k = e >> 10;
        float v = cb[k * NCODES + n];       // coalesced in n
        cbT[n * DIM + k] = v;
        ch[n * DIM + k]  = (_Float16)v;
    } else if (b < 516) {
        int n = (b - 512) * 256 + threadIdx.x;   // 0..1023
        float acc = 0.f;
        for (int k = 0; k < DIM; ++k)
            acc = acc + sqf(cb[k * NCODES + n]); // np axis-0 order
        cc[n] = acc;
        if (n == 0) *cnt = 0;
    } else {
        int s = (b - 516) * 256 + threadIdx.x;   // 0..16383
        bst[s] = 0xFFFFFFFFFFFFFFFFull;
    }
}

// ---------------------------------------------------------------------------
// Phase 1: fp16 MFMA scoring, fused top-2 argmin (unchanged from round 1).
// 1024 blocks x 4 waves, 32 rows/wave; B chunks double-buffered via
// global_load_lds with XOR-swizzled global source + swizzled ds_read.
// ---------------------------------------------------------------------------
__device__ __forceinline__ void stage_chunk(const _Float16* __restrict__ ch,
                                            _Float16* lds,
                                            int chunk, int w, int quad, int lane15) {
#pragma unroll
    for (int i = 0; i < 4; ++i) {
        int r = (w << 4) + (i << 2) + quad;          // code row 0..63 of chunk
        const _Float16* g = ch + (size_t)(chunk * NCHUNK + r) * DIM
                               + ((lane15 ^ (r & 7)) << 3);
        __builtin_amdgcn_global_load_lds(
            (const __attribute__((address_space(1))) void*)g,
            (__attribute__((address_space(3))) void*)(lds + (w << 11) + (i << 9)),
            16, 0, 0);
    }
}

__global__ __launch_bounds__(256, 4) void vq_gemm(const float* __restrict__ x,
                                                  const _Float16* __restrict__ ch,
                                                  const float* __restrict__ cc,
                                                  int* __restrict__ idx,
                                                  int* __restrict__ cnt,
                                                  int* __restrict__ wl) {
    __shared__ _Float16 bs[2][NCHUNK * DIM];   // 2 x 16 KB double buffer

    const int t      = threadIdx.x;
    const int w      = t >> 6;
    const int L      = t & 63;
    const int lane15 = L & 15;
    const int quad   = L >> 4;
    const int rowbase = blockIdx.x * MTILE + w * 32;

    stage_chunk(ch, bs[0], 0, w, quad, lane15);

    half8 af[2][4];
#pragma unroll
    for (int m = 0; m < 2; ++m) {
#pragma unroll
        for (int ks = 0; ks < 4; ++ks) {
            const float* src = x + (size_t)(rowbase + m * 16 + lane15) * DIM
                                 + ks * 32 + quad * 8;
            float4 f0 = *(const float4*)src;
            float4 f1 = *(const float4*)(src + 4);
            half8 h;
            h[0] = (_Float16)f0.x; h[1] = (_Float16)f0.y;
            h[2] = (_Float16)f0.z; h[3] = (_Float16)f0.w;
            h[4] = (_Float16)f1.x; h[5] = (_Float16)f1.y;
            h[6] = (_Float16)f1.z; h[7] = (_Float16)f1.w;
            af[m][ks] = h;
        }
    }

    int roff[4];
#pragma unroll
    for (int ks = 0; ks < 4; ++ks)
        roff[ks] = lane15 * DIM + ((((ks << 2) + quad) ^ (lane15 & 7)) << 3);

    unsigned p1[2][4], p2[2][4];
#pragma unroll
    for (int m = 0; m < 2; ++m)
#pragma unroll
        for (int r = 0; r < 4; ++r) { p1[m][r] = 0xFFFFFFFFu; p2[m][r] = 0xFFFFFFFFu; }

    __syncthreads();   // chunk 0 resident

#pragma unroll 2
    for (int c = 0; c < NCODES / NCHUNK; ++c) {
        if (c + 1 < NCODES / NCHUNK)
            stage_chunk(ch, bs[(c + 1) & 1], c + 1, w, quad, lane15);   // async

        float cc4[4];
#pragma unroll
        for (int j = 0; j < 4; ++j)
            cc4[j] = cc[c * NCHUNK + j * 16 + lane15] + 4.0f;

        const _Float16* bp = bs[c & 1];
        f32x4 acc[2][4];
#pragma unroll
        for (int m = 0; m < 2; ++m)
#pragma unroll
            for (int j = 0; j < 4; ++j) {
                f32x4 z = {0.f, 0.f, 0.f, 0.f};
                acc[m][j] = z;
            }

#pragma unroll
        for (int ks = 0; ks < 4; ++ks) {
            half8 bf[4];
#pragma unroll
            for (int j = 0; j < 4; ++j)
                bf[j] = *(const half8*)(bp + (j << 11) + roff[ks]);
#pragma unroll
            for (int j = 0; j < 4; ++j)
#pragma unroll
                for (int m = 0; m < 2; ++m)
                    acc[m][j] = __builtin_amdgcn_mfma_f32_16x16x32_f16(af[m][ks], bf[j], acc[m][j], 0, 0, 0);
        }

#pragma unroll
        for (int j = 0; j < 4; ++j) {
            int col = c * NCHUNK + j * 16 + lane15;
#pragma unroll
            for (int m = 0; m < 2; ++m)
#pragma unroll
                for (int r = 0; r < 4; ++r) {
                    float s = fmaf(-2.0f, acc[m][j][r], cc4[j]);
                    s = fmaxf(s, 0.25f);
                    unsigned up = (__float_as_uint(s) & 0xFFFFFC00u) | (unsigned)col;
                    unsigned a  = p1[m][r];
                    unsigned lo = a < up ? a : up;
                    unsigned hi = a < up ? up : a;
                    p1[m][r] = lo;
                    p2[m][r] = p2[m][r] < hi ? p2[m][r] : hi;
                }
        }
        __syncthreads();
    }

#pragma unroll
    for (int m = 0; m < 2; ++m)
#pragma unroll
        for (int r = 0; r < 4; ++r) {
            unsigned a1 = p1[m][r], a2 = p2[m][r];
#pragma unroll
            for (int mask = 1; mask <= 8; mask <<= 1) {
                unsigned b1 = (unsigned)__shfl_xor((int)a1, mask, 64);
                unsigned b2 = (unsigned)__shfl_xor((int)a2, mask, 64);
                unsigned n1 = a1 < b1 ? a1 : b1;
                unsigned hi = a1 < b1 ? b1 : a1;
                unsigned mn = a2 < b2 ? a2 : b2;
                unsigned n2 = hi < mn ? hi : mn;
                a1 = n1; a2 = n2;
            }
            if (lane15 == 0) {
                int row = rowbase + m * 16 + quad * 4 + r;
                idx[row] = (int)(a1 & 0x3FFu);
                float s1 = __uint_as_float(a1 & 0xFFFFFC00u);
                float s2 = __uint_as_float(a2 & 0xFFFFFC00u);
                if (s2 - s1 < M_TEST) {
                    int slot = atomicAdd(cnt, 1);
                    if (slot < WL_CAP) wl[slot] = row;
                }
            }
        }
}

// ---------------------------------------------------------------------------
// Phase 2 v3: np-exact rescoring, restructured for LDS-pipe efficiency.
//  - Block work item = 64 flagged rows x 256 codes (code quarter).
//    items = ceil(count/64)*4 -> all CUs busy for any count.
//  - Thread tile 4 rows x 4 codes: per k4 step 8 ds_read_b128 feed 64 FMA
//    (8 FMA/read, was 3.2) -> LDS traffic / product cut 2.5x.
//  - xx computed once per row (wave 0), shared via LDS.
//  - Per-quarter row-best merged across blocks by atomicMin on u64 keys;
//    vq_fix writes idx. Per-(row,code) float arithmetic (chain order, d
//    formula, key packing, tie-break) identical to the verified kernel.
// ---------------------------------------------------------------------------
__global__ __launch_bounds__(256, 2) void vq_exact(const float* __restrict__ x,
                                                   const float* __restrict__ cbT,
                                                   const float* __restrict__ cc,
                                                   const int* __restrict__ cnt,
                                                   const int* __restrict__ wl,
                                                   unsigned long long* __restrict__ bst) {
    __shared__ float xsS[GR * CSTR];     // 64 staged x-rows
    __shared__ float cbS[64 * CSTR];     // 64-code chunk
    __shared__ float xxS[GR];

    const int t  = threadIdx.x;
    const int r4 = t >> 4;      // row group 0..15 (rows 4*r4 .. 4*r4+3)
    const int q  = t & 15;      // code residue 0..15

    int count = *cnt;
    if (count > WL_CAP) count = WL_CAP;
    const int ngrp   = (count + GR - 1) / GR;
    const int nitems = ngrp * 4;

    for (int it = blockIdx.x; it < nitems; it += gridDim.x) {
        const int grp = it >> 2;        // row group (consecutive blocks share rows)
        const int cq  = it & 3;         // code quarter

        __syncthreads();   // previous item's xsS readers done
        // Stage 64 x-rows (512B coalesced runs per row).
#pragma unroll
        for (int j = 0; j < 8; ++j) {
            int e  = t + 256 * j;       // float4 index 0..2047
            int rr = e >> 5, k4 = e & 31;
            int sl = grp * GR + rr;
            sl = sl < count ? sl : count - 1;   // clamp: dup rows benign (guarded at merge)
            int rw = wl[sl];
            float4 v = ((const float4*)x)[(size_t)rw * 32 + k4];
            *(float4*)&xsS[rr * CSTR + k4 * 4] = v;
        }
        __syncthreads();

        // xx once per row: numpy pairwise sum, n=128 block, 8 accumulators
        // (verified form), computed by wave 0 (one thread per row).
        if (t < GR) {
            const float* xs = &xsS[t * CSTR];
            float r0 = sqf(xs[0]), r1 = sqf(xs[1]), r2 = sqf(xs[2]), r3 = sqf(xs[3]);
            float r4_ = sqf(xs[4]), r5 = sqf(xs[5]), r6 = sqf(xs[6]), r7 = sqf(xs[7]);
#pragma unroll
            for (int k = 8; k < DIM; k += 8) {
                r0 = r0 + sqf(xs[k + 0]); r1 = r1 + sqf(xs[k + 1]);
                r2 = r2 + sqf(xs[k + 2]); r3 = r3 + sqf(xs[k + 3]);
                r4_ = r4_ + sqf(xs[k + 4]); r5 = r5 + sqf(xs[k + 5]);
                r6 = r6 + sqf(xs[k + 6]); r7 = r7 + sqf(xs[k + 7]);
            }
            xxS[t] = ((r0 + r1) + (r2 + r3)) + ((r4_ + r5) + (r6 + r7));
        }
        __syncthreads();

        float xxv[4];
#pragma unroll
        for (int i = 0; i < 4; ++i) xxv[i] = xxS[r4 * 4 + i];

        unsigned long long best[4];
#pragma unroll
        for (int i = 0; i < 4; ++i) best[i] = 0xFFFFFFFFFFFFFFFFull;

        for (int ch = 0; ch < 4; ++ch) {
            const int nb = cq * 256 + ch * 64;      // global code base of chunk
            __syncthreads();   // previous chunk's cbS readers done
#pragma unroll
            for (int j = 0; j < 8; ++j) {
                int e  = t + 256 * j;               // float4 index 0..2047
                int ci = e >> 5, k4 = e & 31;
                float4 v = ((const float4*)cbT)[(size_t)(nb + ci) * 32 + k4];
                *(float4*)&cbS[ci * CSTR + k4 * 4] = v;
            }
            __syncthreads();

            // 16 sequential k-ascending fmaf chains (np/BLAS order per pair).
            float a[4][4];
#pragma unroll
            for (int i = 0; i < 4; ++i)
#pragma unroll
                for (int j = 0; j < 4; ++j) a[i][j] = 0.f;

#pragma unroll 4
            for (int k4 = 0; k4 < 32; ++k4) {
                float4 xv[4], cv[4];
#pragma unroll
                for (int i = 0; i < 4; ++i)
                    xv[i] = *(const float4*)&xsS[(r4 * 4 + i) * CSTR + k4 * 4];
#pragma unroll
                for (int j = 0; j < 4; ++j)
                    cv[j] = *(const float4*)&cbS[(q + 16 * j) * CSTR + k4 * 4];
#pragma unroll
                for (int i = 0; i < 4; ++i)
#pragma unroll
                    for (int j = 0; j < 4; ++j) {
                        float acc = a[i][j];
                        acc = fmaf(cv[j].x, xv[i].x, acc);
                        acc = fmaf(cv[j].y, xv[i].y, acc);
                        acc = fmaf(cv[j].z, xv[i].z, acc);
                        acc = fmaf(cv[j].w, xv[i].w, acc);
                        a[i][j] = acc;
                    }
            }

#pragma unroll
            for (int j = 0; j < 4; ++j) {
                int n = nb + q + 16 * j;
                float ccn = cc[n];
#pragma unroll
                for (int i = 0; i < 4; ++i) {
                    float tt = xxv[i] + ccn;
                    float d  = tt - (a[i][j] + a[i][j]);
                    unsigned u  = __float_as_uint(d);
                    unsigned mk = (unsigned)(((int)u) >> 31);
                    unsigned f  = u ^ (mk | 0x80000000u);
                    unsigned long long key = ((unsigned long long)f << 32) | (unsigned)n;
                    best[i] = key < best[i] ? key : best[i];
                }
            }
        }

        // Reduce over the 16 q-lanes (contiguous lane group), then merge.
#pragma unroll
        for (int i = 0; i < 4; ++i) {
            unsigned long long b = best[i];
#pragma unroll
            for (int mask = 1; mask <= 8; mask <<= 1) {
                unsigned long long o =
                    (unsigned long long)__shfl_xor((long long)b, mask, 64);
                b = o < b ? o : b;
            }
            if (q == 0) {
                int sl = grp * GR + r4 * 4 + i;
                if (sl < count) atomicMin(&bst[sl], b);
            }
        }
    }
}

// ---------------------------------------------------------------------------
// Phase 2b: write merged winners into idx.
// ---------------------------------------------------------------------------
__global__ void vq_fix(const int* __restrict__ cnt,
                       const int* __restrict__ wl,
                       const unsigned long long* __restrict__ bst,
                       int* __restrict__ idx) {
    int count = *cnt;
    if (count > WL_CAP) count = WL_CAP;
    for (int s = blockIdx.x * 256 + threadIdx.x; s < count; s += gridDim.x * 256)
        idx[wl[s]] = (int)(bst[s] & 0xFFFFFFFFull);
}

// ---------------------------------------------------------------------------
// Phase 3: out = q (codebook column idx[row]); |q - (x + fl(q-x))| <= 4e-7,
// well under the 1e-3 threshold, and skips the 64 MB x read.
// ---------------------------------------------------------------------------
__global__ void vq_out(const float* __restrict__ cbT,
                       const int* __restrict__ idx,
                       float* __restrict__ out) {
    size_t e = (size_t)blockIdx.x * 256 + threadIdx.x;   // float4 index
    int row = (int)(e >> 5);
    int k4  = (int)(e & 31);
    ((float4*)out)[e] = ((const float4*)cbT)[(size_t)idx[row] * 32 + k4];
}

// ---------------------------------------------------------------------------
extern "C" void kernel_launch(void* const* d_in, const int* in_sizes, int n_in,
                              void* d_out, int out_size, void* d_ws, size_t ws_size,
                              hipStream_t stream) {
    const float* x  = (const float*)d_in[0];   // [131072,128] f32
    const float* cb = (const float*)d_in[1];   // [128,1024] f32
    float* out = (float*)d_out;

    char* p = (char*)d_ws;
    float*    cbT = (float*)p;               p += NCODES * DIM * sizeof(float);
    _Float16* ch  = (_Float16*)p;            p += NCODES * DIM * sizeof(_Float16);
    float*    cc  = (float*)p;               p += NCODES * sizeof(float);
    int*      idx = (int*)p;                 p += M_ROWS * sizeof(int);
    int*      cnt = (int*)p;                 p += 16 * sizeof(int);
    int*      wl  = (int*)p;                 p += WL_CAP * sizeof(int);
    unsigned long long* bst = (unsigned long long*)p;

    vq_prep<<<580, 256, 0, stream>>>(cb, cbT, ch, cc, cnt, bst);
    vq_gemm<<<M_ROWS / MTILE, 256, 0, stream>>>(x, ch, cc, idx, cnt, wl);
    vq_exact<<<512, 256, 0, stream>>>(x, cbT, cc, cnt, wl, bst);
    vq_fix<<<64, 256, 0, stream>>>(cnt, wl, bst, idx);
    vq_out<<<(M_ROWS * (DIM / 4)) / 256, 256, 0, stream>>>(cbT, idx, out);
}

// Round 3
// 186.074 us; speedup vs baseline: 1.3527x; 1.0601x over previous
//
#include <hip/hip_runtime.h>
#include <math.h>

typedef _Float16 half8 __attribute__((ext_vector_type(8)));
typedef float    f32x4 __attribute__((ext_vector_type(4)));

#define DIM     128
#define NCODES  1024
#define M_ROWS  (32*64*64)   // 131072
#define MTILE   128          // rows per block in phase 1 (4 waves x 32 rows)
#define NCHUNK  64           // codes per LDS chunk in phase 1
#define M_TEST  3.0e-3f      // flag margin (quantized-score gap)
#define WL_CAP  16384
#define GR      64           // flagged rows per vq_exact block
#define CSTR    132          // f32 LDS stride (528 B, 16B aligned; worst alias 2-way = free)

// fl32(v*v), immune to FMA contraction (f64 product exact, one rounding).
__device__ __forceinline__ float sqf(float v) {
    return (float)((double)v * (double)v);
}

// ---------------------------------------------------------------------------
// Prep: blocks 0..511 transpose cb->cbT (f32) and ch (fp16), one elem/thread.
// Blocks 512..515: cc[n] = np axis-0 sequential sum of rounded squares.
// Blocks 516..579: init bst[] (per-flagged-row best key) to all-ones.
// ---------------------------------------------------------------------------
__global__ void vq_prep(const float* __restrict__ cb,
                        float* __restrict__ cbT,
                        _Float16* __restrict__ ch,
                        float* __restrict__ cc,
                        int* __restrict__ cnt,
                        unsigned long long* __restrict__ bst) {
    const int b = blockIdx.x;
    if (b < 512) {
        int e = b * 256 + threadIdx.x;      // 0..131071
        int n = e & 1023, k = e >> 10;
        float v = cb[k * NCODES + n];       // coalesced in n
        cbT[n * DIM + k] = v;
        ch[n * DIM + k]  = (_Float16)v;
    } else if (b < 516) {
        int n = (b - 512) * 256 + threadIdx.x;   // 0..1023
        float acc = 0.f;
        for (int k = 0; k < DIM; ++k)
            acc = acc + sqf(cb[k * NCODES + n]); // np axis-0 order
        cc[n] = acc;
        if (n == 0) *cnt = 0;
    } else {
        int s = (b - 516) * 256 + threadIdx.x;   // 0..16383
        bst[s] = 0xFFFFFFFFFFFFFFFFull;
    }
}

// ---------------------------------------------------------------------------
// Phase 1 v3: fp16 MFMA scoring, fused top-2 argmin.
//  - cc (+4.0f folded) staged to LDS ONCE: the K-loop has no global loads,
//    so vmcnt belongs exclusively to the prefetch DMA and only drains at the
//    barrier (where it has already landed). Round-2's per-chunk cc global
//    loads forced a full DMA drain every chunk (vmcnt FIFO).
//  - __launch_bounds__(256,2): round-2's (256,4) made the allocator split
//    64 VGPR + 64 AGPR and spill af (WRITE_SIZE 0.6->8.8 MB). ~116 live regs
//    fit 4 waves/EU without the forced floor.
// Per-(row,code) arithmetic bit-identical (same fp16 inputs, MFMA k-order,
// score formula incl. the +4.0f rounding, pack, top-2 order).
// ---------------------------------------------------------------------------
__device__ __forceinline__ void stage_chunk(const _Float16* __restrict__ ch,
                                            _Float16* lds,
                                            int chunk, int w, int quad, int lane15) {
#pragma unroll
    for (int i = 0; i < 4; ++i) {
        int r = (w << 4) + (i << 2) + quad;          // code row 0..63 of chunk
        const _Float16* g = ch + (size_t)(chunk * NCHUNK + r) * DIM
                               + ((lane15 ^ (r & 7)) << 3);
        __builtin_amdgcn_global_load_lds(
            (const __attribute__((address_space(1))) void*)g,
            (__attribute__((address_space(3))) void*)(lds + (w << 11) + (i << 9)),
            16, 0, 0);
    }
}

__global__ __launch_bounds__(256, 2) void vq_gemm(const float* __restrict__ x,
                                                  const _Float16* __restrict__ ch,
                                                  const float* __restrict__ cc,
                                                  int* __restrict__ idx,
                                                  int* __restrict__ cnt,
                                                  int* __restrict__ wl) {
    __shared__ _Float16 bs[2][NCHUNK * DIM];   // 2 x 16 KB double buffer
    __shared__ float ccL[NCODES];              // 4 KB (36.25 KB total: 4 blocks/CU)

    const int t      = threadIdx.x;
    const int w      = t >> 6;
    const int L      = t & 63;
    const int lane15 = L & 15;
    const int quad   = L >> 4;
    const int rowbase = blockIdx.x * MTILE + w * 32;

    stage_chunk(ch, bs[0], 0, w, quad, lane15);

    // cc+4 into LDS once (same f32 add as the old per-chunk cc4 computation).
#pragma unroll
    for (int i = 0; i < 4; ++i)
        ccL[t + 256 * i] = cc[t + 256 * i] + 4.0f;

    half8 af[2][4];
#pragma unroll
    for (int m = 0; m < 2; ++m) {
#pragma unroll
        for (int ks = 0; ks < 4; ++ks) {
            const float* src = x + (size_t)(rowbase + m * 16 + lane15) * DIM
                                 + ks * 32 + quad * 8;
            float4 f0 = *(const float4*)src;
            float4 f1 = *(const float4*)(src + 4);
            half8 h;
            h[0] = (_Float16)f0.x; h[1] = (_Float16)f0.y;
            h[2] = (_Float16)f0.z; h[3] = (_Float16)f0.w;
            h[4] = (_Float16)f1.x; h[5] = (_Float16)f1.y;
            h[6] = (_Float16)f1.z; h[7] = (_Float16)f1.w;
            af[m][ks] = h;
        }
    }

    int roff[4];
#pragma unroll
    for (int ks = 0; ks < 4; ++ks)
        roff[ks] = lane15 * DIM + ((((ks << 2) + quad) ^ (lane15 & 7)) << 3);

    unsigned p1[2][4], p2[2][4];
#pragma unroll
    for (int m = 0; m < 2; ++m)
#pragma unroll
        for (int r = 0; r < 4; ++r) { p1[m][r] = 0xFFFFFFFFu; p2[m][r] = 0xFFFFFFFFu; }

    __syncthreads();   // chunk-0 DMA + ccL writes resident

    for (int c = 0; c < NCODES / NCHUNK; ++c) {
        if (c + 1 < NCODES / NCHUNK)
            stage_chunk(ch, bs[(c + 1) & 1], c + 1, w, quad, lane15);   // async

        float cc4[4];
#pragma unroll
        for (int j = 0; j < 4; ++j)
            cc4[j] = ccL[c * NCHUNK + j * 16 + lane15];   // ds_read, broadcast-free

        const _Float16* bp = bs[c & 1];
        f32x4 acc[2][4];
#pragma unroll
        for (int m = 0; m < 2; ++m)
#pragma unroll
            for (int j = 0; j < 4; ++j) {
                f32x4 z = {0.f, 0.f, 0.f, 0.f};
                acc[m][j] = z;
            }

#pragma unroll
        for (int ks = 0; ks < 4; ++ks) {
            half8 bf[4];
#pragma unroll
            for (int j = 0; j < 4; ++j)
                bf[j] = *(const half8*)(bp + (j << 11) + roff[ks]);
#pragma unroll
            for (int j = 0; j < 4; ++j)
#pragma unroll
                for (int m = 0; m < 2; ++m)
                    acc[m][j] = __builtin_amdgcn_mfma_f32_16x16x32_f16(af[m][ks], bf[j], acc[m][j], 0, 0, 0);
        }

#pragma unroll
        for (int j = 0; j < 4; ++j) {
            int col = c * NCHUNK + j * 16 + lane15;
#pragma unroll
            for (int m = 0; m < 2; ++m)
#pragma unroll
                for (int r = 0; r < 4; ++r) {
                    float s = fmaf(-2.0f, acc[m][j][r], cc4[j]);
                    s = fmaxf(s, 0.25f);
                    unsigned up = (__float_as_uint(s) & 0xFFFFFC00u) | (unsigned)col;
                    unsigned a  = p1[m][r];
                    unsigned lo = a < up ? a : up;
                    unsigned hi = a < up ? up : a;
                    p1[m][r] = lo;
                    p2[m][r] = p2[m][r] < hi ? p2[m][r] : hi;
                }
        }
        __syncthreads();   // readers done; DMA c+1 drained (already landed)
    }

#pragma unroll
    for (int m = 0; m < 2; ++m)
#pragma unroll
        for (int r = 0; r < 4; ++r) {
            unsigned a1 = p1[m][r], a2 = p2[m][r];
#pragma unroll
            for (int mask = 1; mask <= 8; mask <<= 1) {
                unsigned b1 = (unsigned)__shfl_xor((int)a1, mask, 64);
                unsigned b2 = (unsigned)__shfl_xor((int)a2, mask, 64);
                unsigned n1 = a1 < b1 ? a1 : b1;
                unsigned hi = a1 < b1 ? b1 : a1;
                unsigned mn = a2 < b2 ? a2 : b2;
                unsigned n2 = hi < mn ? hi : mn;
                a1 = n1; a2 = n2;
            }
            if (lane15 == 0) {
                int row = rowbase + m * 16 + quad * 4 + r;
                idx[row] = (int)(a1 & 0x3FFu);
                float s1 = __uint_as_float(a1 & 0xFFFFFC00u);
                float s2 = __uint_as_float(a2 & 0xFFFFFC00u);
                if (s2 - s1 < M_TEST) {
                    int slot = atomicAdd(cnt, 1);
                    if (slot < WL_CAP) wl[slot] = row;
                }
            }
        }
}

// ---------------------------------------------------------------------------
// Phase 2 v3: np-exact rescoring (unchanged from round 2).
// Block item = 64 flagged rows x 256 codes; thread tile 4x4; atomicMin merge.
// ---------------------------------------------------------------------------
__global__ __launch_bounds__(256, 2) void vq_exact(const float* __restrict__ x,
                                                   const float* __restrict__ cbT,
                                                   const float* __restrict__ cc,
                                                   const int* __restrict__ cnt,
                                                   const int* __restrict__ wl,
                                                   unsigned long long* __restrict__ bst) {
    __shared__ float xsS[GR * CSTR];     // 64 staged x-rows
    __shared__ float cbS[64 * CSTR];     // 64-code chunk
    __shared__ float xxS[GR];

    const int t  = threadIdx.x;
    const int r4 = t >> 4;      // row group 0..15 (rows 4*r4 .. 4*r4+3)
    const int q  = t & 15;      // code residue 0..15

    int count = *cnt;
    if (count > WL_CAP) count = WL_CAP;
    const int ngrp   = (count + GR - 1) / GR;
    const int nitems = ngrp * 4;

    for (int it = blockIdx.x; it < nitems; it += gridDim.x) {
        const int grp = it >> 2;        // row group (consecutive blocks share rows)
        const int cq  = it & 3;         // code quarter

        __syncthreads();   // previous item's xsS readers done
#pragma unroll
        for (int j = 0; j < 8; ++j) {
            int e  = t + 256 * j;       // float4 index 0..2047
            int rr = e >> 5, k4 = e & 31;
            int sl = grp * GR + rr;
            sl = sl < count ? sl : count - 1;   // clamp: dup rows benign (guarded at merge)
            int rw = wl[sl];
            float4 v = ((const float4*)x)[(size_t)rw * 32 + k4];
            *(float4*)&xsS[rr * CSTR + k4 * 4] = v;
        }
        __syncthreads();

        // xx once per row: numpy pairwise sum, n=128 block, 8 accumulators
        // (verified form), computed by wave 0 (one thread per row).
        if (t < GR) {
            const float* xs = &xsS[t * CSTR];
            float r0 = sqf(xs[0]), r1 = sqf(xs[1]), r2 = sqf(xs[2]), r3 = sqf(xs[3]);
            float r4_ = sqf(xs[4]), r5 = sqf(xs[5]), r6 = sqf(xs[6]), r7 = sqf(xs[7]);
#pragma unroll
            for (int k = 8; k < DIM; k += 8) {
                r0 = r0 + sqf(xs[k + 0]); r1 = r1 + sqf(xs[k + 1]);
                r2 = r2 + sqf(xs[k + 2]); r3 = r3 + sqf(xs[k + 3]);
                r4_ = r4_ + sqf(xs[k + 4]); r5 = r5 + sqf(xs[k + 5]);
                r6 = r6 + sqf(xs[k + 6]); r7 = r7 + sqf(xs[k + 7]);
            }
            xxS[t] = ((r0 + r1) + (r2 + r3)) + ((r4_ + r5) + (r6 + r7));
        }
        __syncthreads();

        float xxv[4];
#pragma unroll
        for (int i = 0; i < 4; ++i) xxv[i] = xxS[r4 * 4 + i];

        unsigned long long best[4];
#pragma unroll
        for (int i = 0; i < 4; ++i) best[i] = 0xFFFFFFFFFFFFFFFFull;

        for (int ch = 0; ch < 4; ++ch) {
            const int nb = cq * 256 + ch * 64;      // global code base of chunk
            __syncthreads();   // previous chunk's cbS readers done
#pragma unroll
            for (int j = 0; j < 8; ++j) {
                int e  = t + 256 * j;               // float4 index 0..2047
                int ci = e >> 5, k4 = e & 31;
                float4 v = ((const float4*)cbT)[(size_t)(nb + ci) * 32 + k4];
                *(float4*)&cbS[ci * CSTR + k4 * 4] = v;
            }
            __syncthreads();

            float a[4][4];
#pragma unroll
            for (int i = 0; i < 4; ++i)
#pragma unroll
                for (int j = 0; j < 4; ++j) a[i][j] = 0.f;

#pragma unroll 4
            for (int k4 = 0; k4 < 32; ++k4) {
                float4 xv[4], cv[4];
#pragma unroll
                for (int i = 0; i < 4; ++i)
                    xv[i] = *(const float4*)&xsS[(r4 * 4 + i) * CSTR + k4 * 4];
#pragma unroll
                for (int j = 0; j < 4; ++j)
                    cv[j] = *(const float4*)&cbS[(q + 16 * j) * CSTR + k4 * 4];
#pragma unroll
                for (int i = 0; i < 4; ++i)
#pragma unroll
                    for (int j = 0; j < 4; ++j) {
                        float acc = a[i][j];
                        acc = fmaf(cv[j].x, xv[i].x, acc);
                        acc = fmaf(cv[j].y, xv[i].y, acc);
                        acc = fmaf(cv[j].z, xv[i].z, acc);
                        acc = fmaf(cv[j].w, xv[i].w, acc);
                        a[i][j] = acc;
                    }
            }

#pragma unroll
            for (int j = 0; j < 4; ++j) {
                int n = nb + q + 16 * j;
                float ccn = cc[n];
#pragma unroll
                for (int i = 0; i < 4; ++i) {
                    float tt = xxv[i] + ccn;
                    float d  = tt - (a[i][j] + a[i][j]);
                    unsigned u  = __float_as_uint(d);
                    unsigned mk = (unsigned)(((int)u) >> 31);
                    unsigned f  = u ^ (mk | 0x80000000u);
                    unsigned long long key = ((unsigned long long)f << 32) | (unsigned)n;
                    best[i] = key < best[i] ? key : best[i];
                }
            }
        }

#pragma unroll
        for (int i = 0; i < 4; ++i) {
            unsigned long long b = best[i];
#pragma unroll
            for (int mask = 1; mask <= 8; mask <<= 1) {
                unsigned long long o =
                    (unsigned long long)__shfl_xor((long long)b, mask, 64);
                b = o < b ? o : b;
            }
            if (q == 0) {
                int sl = grp * GR + r4 * 4 + i;
                if (sl < count) atomicMin(&bst[sl], b);
            }
        }
    }
}

// ---------------------------------------------------------------------------
// Phase 2b: write merged winners into idx.
// ---------------------------------------------------------------------------
__global__ void vq_fix(const int* __restrict__ cnt,
                       const int* __restrict__ wl,
                       const unsigned long long* __restrict__ bst,
                       int* __restrict__ idx) {
    int count = *cnt;
    if (count > WL_CAP) count = WL_CAP;
    for (int s = blockIdx.x * 256 + threadIdx.x; s < count; s += gridDim.x * 256)
        idx[wl[s]] = (int)(bst[s] & 0xFFFFFFFFull);
}

// ---------------------------------------------------------------------------
// Phase 3: out = q (codebook column idx[row]); |q - (x + fl(q-x))| <= 4e-7,
// well under the 1e-3 threshold, and skips the 64 MB x read.
// ---------------------------------------------------------------------------
__global__ void vq_out(const float* __restrict__ cbT,
                       const int* __restrict__ idx,
                       float* __restrict__ out) {
    size_t e = (size_t)blockIdx.x * 256 + threadIdx.x;   // float4 index
    int row = (int)(e >> 5);
    int k4  = (int)(e & 31);
    ((float4*)out)[e] = ((const float4*)cbT)[(size_t)idx[row] * 32 + k4];
}

// ---------------------------------------------------------------------------
extern "C" void kernel_launch(void* const* d_in, const int* in_sizes, int n_in,
                              void* d_out, int out_size, void* d_ws, size_t ws_size,
                              hipStream_t stream) {
    const float* x  = (const float*)d_in[0];   // [131072,128] f32
    const float* cb = (const float*)d_in[1];   // [128,1024] f32
    float* out = (float*)d_out;

    char* p = (char*)d_ws;
    float*    cbT = (float*)p;               p += NCODES * DIM * sizeof(float);
    _Float16* ch  = (_Float16*)p;            p += NCODES * DIM * sizeof(_Float16);
    float*    cc  = (float*)p;               p += NCODES * sizeof(float);
    int*      idx = (int*)p;                 p += M_ROWS * sizeof(int);
    int*      cnt = (int*)p;                 p += 16 * sizeof(int);
    int*      wl  = (int*)p;                 p += WL_CAP * sizeof(int);
    unsigned long long* bst = (unsigned long long*)p;

    vq_prep<<<580, 256, 0, stream>>>(cb, cbT, ch, cc, cnt, bst);
    vq_gemm<<<M_ROWS / MTILE, 256, 0, stream>>>(x, ch, cc, idx, cnt, wl);
    vq_exact<<<512, 256, 0, stream>>>(x, cbT, cc, cnt, wl, bst);
    vq_fix<<<64, 256, 0, stream>>>(cnt, wl, bst, idx);
    vq_out<<<(M_ROWS * (DIM / 4)) / 256, 256, 0, stream>>>(cbT, idx, out);
}